// Round 21
// baseline (74.006 us; speedup 1.0000x reference)
//
#include <hip/hip_runtime.h>
#include <hip/hip_bf16.h>

#define NN 20000
#define NE 160000
#define CAP 4096     // slots per bucket (mean 2500, sd ~50)
#define CAPR 32      // msg slots per output row (deg mean 8, max ~21)
#define CPB 6        // k_main slots per (bucket,half): 64*2*6 = 768 blocks = 3/CU exact

typedef __attribute__((ext_vector_type(8))) short short8;
typedef __attribute__((ext_vector_type(4))) float floatx4;

__device__ __forceinline__ unsigned short f2bf_rn(float f) {
    __hip_bfloat16 h = __float2bfloat16(f);
    return __builtin_bit_cast(unsigned short, h);
}
__device__ __forceinline__ float bf2f(unsigned short u) {
    return __uint_as_float(((unsigned)u) << 16);
}

// ---------------- K0: x -> bf16 (coalesced) + zero degi/curp ----------------
__global__ void k_pre(const float* __restrict__ x, unsigned short* __restrict__ xbf,
                      int* __restrict__ degi, int* __restrict__ curp) {
    int gi = blockIdx.x * 256 + threadIdx.x;       // 625*256 = 160,000 threads
    if (gi < NN) degi[gi] = 0;
    if (gi < 2048) curp[gi] = 0;
    size_t base = (size_t)gi * 8;                  // covers 1,280,000 elems exactly
    const float4* xr = (const float4*)(x + base);
    float4 v0 = xr[0], v1 = xr[1];
    short8 pk;
    pk[0]=(short)f2bf_rn(v0.x); pk[1]=(short)f2bf_rn(v0.y);
    pk[2]=(short)f2bf_rn(v0.z); pk[3]=(short)f2bf_rn(v0.w);
    pk[4]=(short)f2bf_rn(v1.x); pk[5]=(short)f2bf_rn(v1.y);
    pk[6]=(short)f2bf_rn(v1.z); pk[7]=(short)f2bf_rn(v1.w);
    *(short8*)(xbf + base) = pk;
}

// ---------------- K1: prep (0-624) + W-permute (625-752) + x@root->out (753-1065) ----------------
__global__ void k_prep(const float* __restrict__ x,
                       const int* __restrict__ ei, const float* __restrict__ pseudo,
                       int* __restrict__ curp, int* __restrict__ degi,
                       const float* __restrict__ weight, const float* __restrict__ root,
                       float* __restrict__ basisg, unsigned int* __restrict__ rowrp,
                       int* __restrict__ coli, unsigned short* __restrict__ wfg,
                       float* __restrict__ out) {
    int blk = blockIdx.x;
    int tid = threadIdx.x;

    if (blk >= 753) {
        // x@root via MFMA (A = x-tile, B = root fragments), fp32 into out
        __shared__ unsigned short rb[4096];   // 8 KB
        for (int idx = tid; idx < 4096; idx += 256) {
            int fi = idx >> 9;                 // ks*4+nt
            int ks = fi >> 2, nt = fi & 3;
            int lj = idx & 511, ll = lj >> 3, j = lj & 7;
            int k = ks*32 + (ll >> 4)*8 + j;
            int n = nt*16 + (ll & 15);
            rb[idx] = f2bf_rn(root[k*64 + n]);
        }
        __syncthreads();
        int nb = blk - 753;
        int wv = tid >> 6, l = tid & 63, lo = l & 15, g = l >> 4;
        int n0 = nb*64 + wv*16;
        int q = min(n0 + lo, NN-1);
        const float4* xr = (const float4*)(x + q*64 + g*8);
        float4 a0 = xr[0], a1 = xr[1];
        const float4* xr2 = (const float4*)(x + q*64 + 32 + g*8);
        float4 c0 = xr2[0], c1 = xr2[1];
        short8 xa, xc;
        xa[0]=(short)f2bf_rn(a0.x); xa[1]=(short)f2bf_rn(a0.y);
        xa[2]=(short)f2bf_rn(a0.z); xa[3]=(short)f2bf_rn(a0.w);
        xa[4]=(short)f2bf_rn(a1.x); xa[5]=(short)f2bf_rn(a1.y);
        xa[6]=(short)f2bf_rn(a1.z); xa[7]=(short)f2bf_rn(a1.w);
        xc[0]=(short)f2bf_rn(c0.x); xc[1]=(short)f2bf_rn(c0.y);
        xc[2]=(short)f2bf_rn(c0.z); xc[3]=(short)f2bf_rn(c0.w);
        xc[4]=(short)f2bf_rn(c1.x); xc[5]=(short)f2bf_rn(c1.y);
        xc[6]=(short)f2bf_rn(c1.z); xc[7]=(short)f2bf_rn(c1.w);
        floatx4 acc[4];
        #pragma unroll
        for (int nt = 0; nt < 4; nt++) acc[nt] = (floatx4){0.f,0.f,0.f,0.f};
        #pragma unroll
        for (int nt = 0; nt < 4; nt++) {
            short8 rb0 = *(const short8*)&rb[(0*4 + nt)*512 + l*8];
            short8 rb1 = *(const short8*)&rb[(1*4 + nt)*512 + l*8];
            acc[nt] = __builtin_amdgcn_mfma_f32_16x16x32_bf16(xa, rb0, acc[nt], 0, 0, 0);
            acc[nt] = __builtin_amdgcn_mfma_f32_16x16x32_bf16(xc, rb1, acc[nt], 0, 0, 0);
        }
        #pragma unroll
        for (int nt = 0; nt < 4; nt++)
            #pragma unroll
            for (int r = 0; r < 4; r++) {
                int n = n0 + 4*g + r;
                if (n < NN) out[n*64 + nt*16 + lo] = acc[nt][r];
            }
        return;
    }

    if (blk >= 625) {
        // W^T fragment permute for k_main's A operand
        int bh = blk - 625;
        int b = bh >> 1, h = bh & 1;
        int wbase = (b & 3) + 5*((b >> 2) & 3) + 25*((b >> 4) & 3);
        int sec = tid >> 3, lg = tid & 7;
        int s = sec >> 2, ks = (sec >> 1) & 1, mt = sec & 1;
        int widx = wbase + (s & 1) + 5*((s >> 1) & 1) + 25*((s >> 2) & 1);
        const float* wm = weight + widx*4096;
        unsigned short tmp[64];
        #pragma unroll
        for (int ll = 0; ll < 8; ll++) {
            int l = lg*8 + ll;
            int cout = h*32 + mt*16 + (l & 15);
            int ib = 32*ks + (l >> 4)*8;
            #pragma unroll
            for (int j = 0; j < 8; j++)
                tmp[ll*8 + j] = f2bf_rn(wm[(ib + j)*64 + cout]);
        }
        unsigned short* dstp = wfg + bh*16384 + sec*512 + lg*64;
        #pragma unroll
        for (int c = 0; c < 8; c++)
            *(short8*)(dstp + c*8) = *(const short8*)(tmp + c*8);
        return;
    }

    // edge placement (light: basis + rowrp + coli only)
    __shared__ int lh[64];
    __shared__ int gb[64];
    if (tid < 64) lh[tid] = 0;
    __syncthreads();
    int e = blk * 256 + tid;
    int a = 0, r = 0;
    float p0 = 0.f, p1 = 0.f, p2 = 0.f;
    if (e < NE) {
        p0 = pseudo[e*3+0]; p1 = pseudo[e*3+1]; p2 = pseudo[e*3+2];
        int v0 = min(3, max(0, (int)floorf(p0 * 4.f)));
        int v1 = min(3, max(0, (int)floorf(p1 * 4.f)));
        int v2 = min(3, max(0, (int)floorf(p2 * 4.f)));
        a = v0 + 4*v1 + 16*v2;
        r = atomicAdd(&lh[a], 1);
    }
    __syncthreads();
    if (tid < 64) gb[tid] = lh[tid] ? atomicAdd(&curp[tid*32], lh[tid]) : 0;
    __syncthreads();
    if (e >= NE) return;
    int idx = gb[a] + r;
    if (idx >= CAP) return;                 // statistically unreachable
    int slot = a*CAP + idx;

    int row = ei[e], col = ei[NE + e];
    int rpos = atomicAdd(&degi[row], 1);
    rowrp[slot] = ((unsigned)row << 10) | (unsigned)rpos;
    coli[slot] = col;

    float va = p0*4.f, vb = p1*4.f, vc = p2*4.f;
    float f0 = va - floorf(va);
    float f1 = vb - floorf(vb);
    float f2 = vc - floorf(vc);
    float bv[8];
    #pragma unroll
    for (int s = 0; s < 8; s++) {
        float t0 = (s & 1) ? f0 : 1.f - f0;
        float t1 = (s & 2) ? f1 : 1.f - f1;
        float t2 = (s & 4) ? f2 : 1.f - f2;
        bv[s] = t0 * t1 * t2;
    }
    float* bp = basisg + (size_t)slot*8;
    *(float4*)(bp)     = (float4){bv[0], bv[1], bv[2], bv[3]};
    *(float4*)(bp + 4) = (float4){bv[4], bv[5], bv[6], bv[7]};
}

// ---------------- K2: main — 64-edge tiles (4 named subtiles share each aw read) ----------------
__global__ __launch_bounds__(256)
void k_main(const unsigned short* __restrict__ wfg, const int* __restrict__ curp,
            const unsigned short* __restrict__ xbf, const float* __restrict__ basisg,
            const unsigned int* __restrict__ rowrp, const int* __restrict__ coli,
            unsigned short* __restrict__ msg) {
    __shared__ unsigned short wf[16384];   // 32 KB A fragments (bucket, half)
    int bh = blockIdx.x & 127;
    int b = bh >> 1, h = bh & 1;
    int slot = blockIdx.x >> 7;            // 0..CPB-1
    {
        const int4* src = (const int4*)(wfg + bh*16384);
        int4* dst = (int4*)wf;
        #pragma unroll
        for (int i = 0; i < 8; i++) dst[i*256 + threadIdx.x] = src[i*256 + threadIdx.x];
    }
    __syncthreads();

    int cnt = min(curp[b*32], CAP);
    int wv = threadIdx.x >> 6;
    int l  = threadIdx.x & 63;
    int lo = l & 15, g = l >> 4;
    const int STRIDE = CPB * 256;          // 1536 edges per pass (wave covers 64)

    const float*        bsb = basisg + (size_t)b*CAP*8;
    const unsigned int* rrb = rowrp + (size_t)b*CAP;
    const int*          clb = coli + (size_t)b*CAP;

#define LOADT(Q, X0, X1, F0, F1, DD)                                        \
    {                                                                        \
        int col_ = min(max(clb[Q], 0), NN-1);      /* clamp pad garbage */   \
        X0 = *(const short8*)(xbf + (size_t)col_*64 + g*8);                  \
        X1 = *(const short8*)(xbf + (size_t)col_*64 + 32 + g*8);             \
        F0 = *(const float4*)(bsb + (size_t)(Q)*8);                          \
        F1 = *(const float4*)(bsb + (size_t)(Q)*8 + 4);                      \
        unsigned rr_ = rrb[Q];                                               \
        DD = (int)(rr_ >> 10) * CAPR + (int)(rr_ & 1023);                    \
    }

    for (int p = slot*256 + wv*64; p < cnt; p += STRIDE) {
        short8 cA0, cA1, cB0, cB1, cC0, cC1, cD0, cD1;
        float4 cfA0, cfA1, cfB0, cfB1, cfC0, cfC1, cfD0, cfD1;
        int cdA, cdB, cdC, cdD;
        LOADT(p + lo,      cA0, cA1, cfA0, cfA1, cdA);
        LOADT(p + 16 + lo, cB0, cB1, cfB0, cfB1, cdB);
        LOADT(p + 32 + lo, cC0, cC1, cfC0, cfC1, cdC);
        LOADT(p + 48 + lo, cD0, cD1, cfD0, cfD1, cdD);

        float fbA[8] = {cfA0.x, cfA0.y, cfA0.z, cfA0.w, cfA1.x, cfA1.y, cfA1.z, cfA1.w};
        float fbB[8] = {cfB0.x, cfB0.y, cfB0.z, cfB0.w, cfB1.x, cfB1.y, cfB1.z, cfB1.w};
        float fbC[8] = {cfC0.x, cfC0.y, cfC0.z, cfC0.w, cfC1.x, cfC1.y, cfC1.z, cfC1.w};
        float fbD[8] = {cfD0.x, cfD0.y, cfD0.z, cfD0.w, cfD1.x, cfD1.y, cfD1.z, cfD1.w};
        float mA0[4] = {0.f,0.f,0.f,0.f};
        float mA1[4] = {0.f,0.f,0.f,0.f};
        float mB0[4] = {0.f,0.f,0.f,0.f};
        float mB1[4] = {0.f,0.f,0.f,0.f};
        float mC0[4] = {0.f,0.f,0.f,0.f};
        float mC1[4] = {0.f,0.f,0.f,0.f};
        float mD0[4] = {0.f,0.f,0.f,0.f};
        float mD1[4] = {0.f,0.f,0.f,0.f};

        #pragma unroll
        for (int s = 0; s < 8; s++) {
            floatx4 aA0 = (floatx4){0.f,0.f,0.f,0.f};
            floatx4 aA1 = (floatx4){0.f,0.f,0.f,0.f};
            floatx4 aB0 = (floatx4){0.f,0.f,0.f,0.f};
            floatx4 aB1 = (floatx4){0.f,0.f,0.f,0.f};
            floatx4 aC0 = (floatx4){0.f,0.f,0.f,0.f};
            floatx4 aC1 = (floatx4){0.f,0.f,0.f,0.f};
            floatx4 aD0 = (floatx4){0.f,0.f,0.f,0.f};
            floatx4 aD1 = (floatx4){0.f,0.f,0.f,0.f};
            short8 aw;
            aw = *(const short8*)&wf[((s*2 + 0)*2 + 0)*512 + l*8];   // ks0, mt0
            aA0 = __builtin_amdgcn_mfma_f32_16x16x32_bf16(aw, cA0, aA0, 0, 0, 0);
            aB0 = __builtin_amdgcn_mfma_f32_16x16x32_bf16(aw, cB0, aB0, 0, 0, 0);
            aC0 = __builtin_amdgcn_mfma_f32_16x16x32_bf16(aw, cC0, aC0, 0, 0, 0);
            aD0 = __builtin_amdgcn_mfma_f32_16x16x32_bf16(aw, cD0, aD0, 0, 0, 0);
            aw = *(const short8*)&wf[((s*2 + 0)*2 + 1)*512 + l*8];   // ks0, mt1
            aA1 = __builtin_amdgcn_mfma_f32_16x16x32_bf16(aw, cA0, aA1, 0, 0, 0);
            aB1 = __builtin_amdgcn_mfma_f32_16x16x32_bf16(aw, cB0, aB1, 0, 0, 0);
            aC1 = __builtin_amdgcn_mfma_f32_16x16x32_bf16(aw, cC0, aC1, 0, 0, 0);
            aD1 = __builtin_amdgcn_mfma_f32_16x16x32_bf16(aw, cD0, aD1, 0, 0, 0);
            aw = *(const short8*)&wf[((s*2 + 1)*2 + 0)*512 + l*8];   // ks1, mt0
            aA0 = __builtin_amdgcn_mfma_f32_16x16x32_bf16(aw, cA1, aA0, 0, 0, 0);
            aB0 = __builtin_amdgcn_mfma_f32_16x16x32_bf16(aw, cB1, aB0, 0, 0, 0);
            aC0 = __builtin_amdgcn_mfma_f32_16x16x32_bf16(aw, cC1, aC0, 0, 0, 0);
            aD0 = __builtin_amdgcn_mfma_f32_16x16x32_bf16(aw, cD1, aD0, 0, 0, 0);
            aw = *(const short8*)&wf[((s*2 + 1)*2 + 1)*512 + l*8];   // ks1, mt1
            aA1 = __builtin_amdgcn_mfma_f32_16x16x32_bf16(aw, cA1, aA1, 0, 0, 0);
            aB1 = __builtin_amdgcn_mfma_f32_16x16x32_bf16(aw, cB1, aB1, 0, 0, 0);
            aC1 = __builtin_amdgcn_mfma_f32_16x16x32_bf16(aw, cC1, aC1, 0, 0, 0);
            aD1 = __builtin_amdgcn_mfma_f32_16x16x32_bf16(aw, cD1, aD1, 0, 0, 0);
            #pragma unroll
            for (int r = 0; r < 4; r++) {
                mA0[r] += fbA[s] * aA0[r];
                mA1[r] += fbA[s] * aA1[r];
                mB0[r] += fbB[s] * aB0[r];
                mB1[r] += fbB[s] * aB1[r];
                mC0[r] += fbC[s] * aC0[r];
                mC1[r] += fbC[s] * aC1[r];
                mD0[r] += fbD[s] * aD0[r];
                mD1[r] += fbD[s] * aD1[r];
            }
        }

        if (p + lo < cnt) {
            ushort4 pk;
            pk.x = f2bf_rn(mA0[0]); pk.y = f2bf_rn(mA0[1]);
            pk.z = f2bf_rn(mA0[2]); pk.w = f2bf_rn(mA0[3]);
            *(ushort4*)(msg + (size_t)cdA*64 + h*32 + 4*g) = pk;
            pk.x = f2bf_rn(mA1[0]); pk.y = f2bf_rn(mA1[1]);
            pk.z = f2bf_rn(mA1[2]); pk.w = f2bf_rn(mA1[3]);
            *(ushort4*)(msg + (size_t)cdA*64 + h*32 + 16 + 4*g) = pk;
        }
        if (p + 16 + lo < cnt) {
            ushort4 pk;
            pk.x = f2bf_rn(mB0[0]); pk.y = f2bf_rn(mB0[1]);
            pk.z = f2bf_rn(mB0[2]); pk.w = f2bf_rn(mB0[3]);
            *(ushort4*)(msg + (size_t)cdB*64 + h*32 + 4*g) = pk;
            pk.x = f2bf_rn(mB1[0]); pk.y = f2bf_rn(mB1[1]);
            pk.z = f2bf_rn(mB1[2]); pk.w = f2bf_rn(mB1[3]);
            *(ushort4*)(msg + (size_t)cdB*64 + h*32 + 16 + 4*g) = pk;
        }
        if (p + 32 + lo < cnt) {
            ushort4 pk;
            pk.x = f2bf_rn(mC0[0]); pk.y = f2bf_rn(mC0[1]);
            pk.z = f2bf_rn(mC0[2]); pk.w = f2bf_rn(mC0[3]);
            *(ushort4*)(msg + (size_t)cdC*64 + h*32 + 4*g) = pk;
            pk.x = f2bf_rn(mC1[0]); pk.y = f2bf_rn(mC1[1]);
            pk.z = f2bf_rn(mC1[2]); pk.w = f2bf_rn(mC1[3]);
            *(ushort4*)(msg + (size_t)cdC*64 + h*32 + 16 + 4*g) = pk;
        }
        if (p + 48 + lo < cnt) {
            ushort4 pk;
            pk.x = f2bf_rn(mD0[0]); pk.y = f2bf_rn(mD0[1]);
            pk.z = f2bf_rn(mD0[2]); pk.w = f2bf_rn(mD0[3]);
            *(ushort4*)(msg + (size_t)cdD*64 + h*32 + 4*g) = pk;
            pk.x = f2bf_rn(mD1[0]); pk.y = f2bf_rn(mD1[1]);
            pk.z = f2bf_rn(mD1[2]); pk.w = f2bf_rn(mD1[3]);
            *(ushort4*)(msg + (size_t)cdD*64 + h*32 + 16 + 4*g) = pk;
        }
    }
#undef LOADT
}

// ---------------- K3: out += rowmean(msg) + bias (fixed-stride rows) ----------------
__global__ void k_final2(const float* __restrict__ bias, const unsigned short* __restrict__ msg,
                         const int* __restrict__ degi, float* __restrict__ out) {
    int n = blockIdx.x * 4 + (threadIdx.x >> 6);
    int o = threadIdx.x & 63;
    int deg = min(degi[n], CAPR);
    const unsigned short* mp = msg + (size_t)n*CAPR*64 + o;
    float v = 0.f;
    for (int j = 0; j < deg; j++) v += bf2f(mp[j*64]);
    v *= 1.0f / (float)max(deg, 1);
    out[n*64 + o] = out[n*64 + o] + v + bias[o];
}

extern "C" void kernel_launch(void* const* d_in, const int* in_sizes, int n_in,
                              void* d_out, int out_size, void* d_ws, size_t ws_size,
                              hipStream_t stream) {
    const float* x      = (const float*)d_in[0];
    const int*   ei     = (const int*)d_in[1];
    const float* pseudo = (const float*)d_in[2];
    const float* weight = (const float*)d_in[3];
    const float* root   = (const float*)d_in[4];
    const float* bias   = (const float*)d_in[5];
    float* out = (float*)d_out;
    char* ws = (char*)d_ws;

    unsigned short* msg    = (unsigned short*)(ws + 0);         // 81,920,000
    float*          basisg = (float*)(ws + 81920000);           // (262144+64)*32 = 8,390,656
    unsigned int*   rowrp  = (unsigned int*)(ws + 90310656);    // 1,048,832
    int*            coli   = (int*)(ws + 91359488);             // 1,048,832
    int*            degi   = (int*)(ws + 92408320);             //    80,000
    int*            curp   = (int*)(ws + 92488320);             //     8,192
    unsigned short* wfg    = (unsigned short*)(ws + 92496512);  // 4,194,304
    unsigned short* xbf    = (unsigned short*)(ws + 96690816);  // 2,560,000 -> 99,250,816 total (ws = 256 MB)

    k_pre   <<<625, 256, 0, stream>>>(x, xbf, degi, curp);
    k_prep  <<<625 + 128 + 313, 256, 0, stream>>>(x, ei, pseudo, curp, degi,
                                                  weight, root, basisg, rowrp, coli, wfg, out);
    k_main  <<<64*2*CPB, 256, 0, stream>>>(wfg, curp, xbf, basisg, rowrp, coli, msg);
    k_final2<<<NN/4, 256, 0, stream>>>(bias, msg, degi, out);
}

// Round 22
// 68.312 us; speedup vs baseline: 1.0834x; 1.0834x over previous
//
#include <hip/hip_runtime.h>
#include <hip/hip_bf16.h>

#define NN 20000
#define NE 160000
#define CAP 4096     // slots per bucket (mean 2500, sd ~50)
#define CAPR 32      // msg slots per output row (deg mean 8, max ~21)
#define CPB 10       // k_main slots per (bucket,half): 64*2*10 = 1280 blocks

typedef __attribute__((ext_vector_type(8))) short short8;
typedef __attribute__((ext_vector_type(4))) float floatx4;

__device__ __forceinline__ unsigned short f2bf_rn(float f) {
    __hip_bfloat16 h = __float2bfloat16(f);
    return __builtin_bit_cast(unsigned short, h);
}
__device__ __forceinline__ float bf2f(unsigned short u) {
    return __uint_as_float(((unsigned)u) << 16);
}

// ---------------- K0: x -> bf16 (coalesced) + zero degi/curp ----------------
__global__ void k_pre(const float* __restrict__ x, unsigned short* __restrict__ xbf,
                      int* __restrict__ degi, int* __restrict__ curp) {
    int gi = blockIdx.x * 256 + threadIdx.x;       // 625*256 = 160,000 threads
    if (gi < NN) degi[gi] = 0;
    if (gi < 2048) curp[gi] = 0;
    size_t base = (size_t)gi * 8;                  // covers 1,280,000 elems exactly
    const float4* xr = (const float4*)(x + base);
    float4 v0 = xr[0], v1 = xr[1];
    short8 pk;
    pk[0]=(short)f2bf_rn(v0.x); pk[1]=(short)f2bf_rn(v0.y);
    pk[2]=(short)f2bf_rn(v0.z); pk[3]=(short)f2bf_rn(v0.w);
    pk[4]=(short)f2bf_rn(v1.x); pk[5]=(short)f2bf_rn(v1.y);
    pk[6]=(short)f2bf_rn(v1.z); pk[7]=(short)f2bf_rn(v1.w);
    *(short8*)(xbf + base) = pk;
}

// ---------------- K1: prep (0-312, 2 edges/thread) + W-permute (313-440) + x@root (441-753) ----------------
__global__ void k_prep(const float* __restrict__ x,
                       const int* __restrict__ ei, const float* __restrict__ pseudo,
                       int* __restrict__ curp, int* __restrict__ degi,
                       const float* __restrict__ weight, const float* __restrict__ root,
                       float* __restrict__ basisg, unsigned int* __restrict__ rowrp,
                       int* __restrict__ coli, unsigned short* __restrict__ wfg,
                       float* __restrict__ out) {
    int blk = blockIdx.x;
    int tid = threadIdx.x;

    if (blk >= 441) {
        // x@root via MFMA (A = x-tile, B = root fragments), fp32 into out
        __shared__ unsigned short rb[4096];   // 8 KB
        for (int idx = tid; idx < 4096; idx += 256) {
            int fi = idx >> 9;                 // ks*4+nt
            int ks = fi >> 2, nt = fi & 3;
            int lj = idx & 511, ll = lj >> 3, j = lj & 7;
            int k = ks*32 + (ll >> 4)*8 + j;
            int n = nt*16 + (ll & 15);
            rb[idx] = f2bf_rn(root[k*64 + n]);
        }
        __syncthreads();
        int nb = blk - 441;
        int wv = tid >> 6, l = tid & 63, lo = l & 15, g = l >> 4;
        int n0 = nb*64 + wv*16;
        int q = min(n0 + lo, NN-1);
        const float4* xr = (const float4*)(x + q*64 + g*8);
        float4 a0 = xr[0], a1 = xr[1];
        const float4* xr2 = (const float4*)(x + q*64 + 32 + g*8);
        float4 c0 = xr2[0], c1 = xr2[1];
        short8 xa, xc;
        xa[0]=(short)f2bf_rn(a0.x); xa[1]=(short)f2bf_rn(a0.y);
        xa[2]=(short)f2bf_rn(a0.z); xa[3]=(short)f2bf_rn(a0.w);
        xa[4]=(short)f2bf_rn(a1.x); xa[5]=(short)f2bf_rn(a1.y);
        xa[6]=(short)f2bf_rn(a1.z); xa[7]=(short)f2bf_rn(a1.w);
        xc[0]=(short)f2bf_rn(c0.x); xc[1]=(short)f2bf_rn(c0.y);
        xc[2]=(short)f2bf_rn(c0.z); xc[3]=(short)f2bf_rn(c0.w);
        xc[4]=(short)f2bf_rn(c1.x); xc[5]=(short)f2bf_rn(c1.y);
        xc[6]=(short)f2bf_rn(c1.z); xc[7]=(short)f2bf_rn(c1.w);
        floatx4 acc[4];
        #pragma unroll
        for (int nt = 0; nt < 4; nt++) acc[nt] = (floatx4){0.f,0.f,0.f,0.f};
        #pragma unroll
        for (int nt = 0; nt < 4; nt++) {
            short8 rb0 = *(const short8*)&rb[(0*4 + nt)*512 + l*8];
            short8 rb1 = *(const short8*)&rb[(1*4 + nt)*512 + l*8];
            acc[nt] = __builtin_amdgcn_mfma_f32_16x16x32_bf16(xa, rb0, acc[nt], 0, 0, 0);
            acc[nt] = __builtin_amdgcn_mfma_f32_16x16x32_bf16(xc, rb1, acc[nt], 0, 0, 0);
        }
        #pragma unroll
        for (int nt = 0; nt < 4; nt++)
            #pragma unroll
            for (int r = 0; r < 4; r++) {
                int n = n0 + 4*g + r;
                if (n < NN) out[n*64 + nt*16 + lo] = acc[nt][r];
            }
        return;
    }

    if (blk >= 313) {
        // W^T fragment permute for k_main's A operand
        int bh = blk - 313;
        int b = bh >> 1, h = bh & 1;
        int wbase = (b & 3) + 5*((b >> 2) & 3) + 25*((b >> 4) & 3);
        int sec = tid >> 3, lg = tid & 7;
        int s = sec >> 2, ks = (sec >> 1) & 1, mt = sec & 1;
        int widx = wbase + (s & 1) + 5*((s >> 1) & 1) + 25*((s >> 2) & 1);
        const float* wm = weight + widx*4096;
        unsigned short tmp[64];
        #pragma unroll
        for (int ll = 0; ll < 8; ll++) {
            int l = lg*8 + ll;
            int cout = h*32 + mt*16 + (l & 15);
            int ib = 32*ks + (l >> 4)*8;
            #pragma unroll
            for (int j = 0; j < 8; j++)
                tmp[ll*8 + j] = f2bf_rn(wm[(ib + j)*64 + cout]);
        }
        unsigned short* dstp = wfg + bh*16384 + sec*512 + lg*64;
        #pragma unroll
        for (int c = 0; c < 8; c++)
            *(short8*)(dstp + c*8) = *(const short8*)(tmp + c*8);
        return;
    }

    // edge placement — 2 edges per thread (512 edges/block)
    __shared__ int lh[64];
    __shared__ int gb[64];
    if (tid < 64) lh[tid] = 0;
    __syncthreads();
    int e0 = blk * 512 + tid;
    int e1 = e0 + 256;
    bool v0e = e0 < NE, v1e = e1 < NE;
    float p00 = 0.f, p01 = 0.f, p02 = 0.f;
    float p10 = 0.f, p11 = 0.f, p12 = 0.f;
    int a0 = 0, a1 = 0, r0 = 0, r1 = 0;
    if (v0e) {
        p00 = pseudo[e0*3+0]; p01 = pseudo[e0*3+1]; p02 = pseudo[e0*3+2];
    }
    if (v1e) {
        p10 = pseudo[e1*3+0]; p11 = pseudo[e1*3+1]; p12 = pseudo[e1*3+2];
    }
    if (v0e) {
        int q0 = min(3, max(0, (int)floorf(p00 * 4.f)));
        int q1 = min(3, max(0, (int)floorf(p01 * 4.f)));
        int q2 = min(3, max(0, (int)floorf(p02 * 4.f)));
        a0 = q0 + 4*q1 + 16*q2;
        r0 = atomicAdd(&lh[a0], 1);
    }
    if (v1e) {
        int q0 = min(3, max(0, (int)floorf(p10 * 4.f)));
        int q1 = min(3, max(0, (int)floorf(p11 * 4.f)));
        int q2 = min(3, max(0, (int)floorf(p12 * 4.f)));
        a1 = q0 + 4*q1 + 16*q2;
        r1 = atomicAdd(&lh[a1], 1);
    }
    __syncthreads();
    if (tid < 64) gb[tid] = lh[tid] ? atomicAdd(&curp[tid*32], lh[tid]) : 0;
    __syncthreads();

    #pragma unroll 1
    for (int ee = 0; ee < 2; ee++) {
        bool live = ee ? v1e : v0e;
        if (!live) continue;
        int e = ee ? e1 : e0;
        int a = ee ? a1 : a0;
        int r = ee ? r1 : r0;
        float pa = ee ? p10 : p00;
        float pb = ee ? p11 : p01;
        float pc = ee ? p12 : p02;
        int idx = gb[a] + r;
        if (idx >= CAP) continue;           // statistically unreachable
        int slot = a*CAP + idx;

        int row = ei[e], col = ei[NE + e];
        int rpos = atomicAdd(&degi[row], 1);
        rowrp[slot] = ((unsigned)row << 10) | (unsigned)rpos;
        coli[slot] = col;

        float va = pa*4.f, vb = pb*4.f, vc = pc*4.f;
        float f0 = va - floorf(va);
        float f1 = vb - floorf(vb);
        float f2 = vc - floorf(vc);
        float bv[8];
        #pragma unroll
        for (int s = 0; s < 8; s++) {
            float t0 = (s & 1) ? f0 : 1.f - f0;
            float t1 = (s & 2) ? f1 : 1.f - f1;
            float t2 = (s & 4) ? f2 : 1.f - f2;
            bv[s] = t0 * t1 * t2;
        }
        float* bp = basisg + (size_t)slot*8;
        *(float4*)(bp)     = (float4){bv[0], bv[1], bv[2], bv[3]};
        *(float4*)(bp + 4) = (float4){bv[4], bv[5], bv[6], bv[7]};
    }
}

// ---------------- K2: main — 64-edge tiles (4 named subtiles share each aw read) ----------------
__global__ __launch_bounds__(256)
void k_main(const unsigned short* __restrict__ wfg, const int* __restrict__ curp,
            const unsigned short* __restrict__ xbf, const float* __restrict__ basisg,
            const unsigned int* __restrict__ rowrp, const int* __restrict__ coli,
            unsigned short* __restrict__ msg) {
    __shared__ unsigned short wf[16384];   // 32 KB A fragments (bucket, half)
    int bh = blockIdx.x & 127;
    int b = bh >> 1, h = bh & 1;
    int slot = blockIdx.x >> 7;            // 0..CPB-1
    {
        const int4* src = (const int4*)(wfg + bh*16384);
        int4* dst = (int4*)wf;
        #pragma unroll
        for (int i = 0; i < 8; i++) dst[i*256 + threadIdx.x] = src[i*256 + threadIdx.x];
    }
    __syncthreads();

    int cnt = min(curp[b*32], CAP);
    int wv = threadIdx.x >> 6;
    int l  = threadIdx.x & 63;
    int lo = l & 15, g = l >> 4;
    const int STRIDE = CPB * 256;          // 2560 edges per pass (wave covers 64)

    const float*        bsb = basisg + (size_t)b*CAP*8;
    const unsigned int* rrb = rowrp + (size_t)b*CAP;
    const int*          clb = coli + (size_t)b*CAP;

#define LOADT(Q, X0, X1, F0, F1, DD)                                        \
    {                                                                        \
        int col_ = min(max(clb[Q], 0), NN-1);      /* clamp pad garbage */   \
        X0 = *(const short8*)(xbf + (size_t)col_*64 + g*8);                  \
        X1 = *(const short8*)(xbf + (size_t)col_*64 + 32 + g*8);             \
        F0 = *(const float4*)(bsb + (size_t)(Q)*8);                          \
        F1 = *(const float4*)(bsb + (size_t)(Q)*8 + 4);                      \
        unsigned rr_ = rrb[Q];                                               \
        DD = (int)(rr_ >> 10) * CAPR + (int)(rr_ & 1023);                    \
    }

    for (int p = slot*256 + wv*64; p < cnt; p += STRIDE) {
        short8 cA0, cA1, cB0, cB1, cC0, cC1, cD0, cD1;
        float4 cfA0, cfA1, cfB0, cfB1, cfC0, cfC1, cfD0, cfD1;
        int cdA, cdB, cdC, cdD;
        LOADT(p + lo,      cA0, cA1, cfA0, cfA1, cdA);
        LOADT(p + 16 + lo, cB0, cB1, cfB0, cfB1, cdB);
        LOADT(p + 32 + lo, cC0, cC1, cfC0, cfC1, cdC);
        LOADT(p + 48 + lo, cD0, cD1, cfD0, cfD1, cdD);

        float fbA[8] = {cfA0.x, cfA0.y, cfA0.z, cfA0.w, cfA1.x, cfA1.y, cfA1.z, cfA1.w};
        float fbB[8] = {cfB0.x, cfB0.y, cfB0.z, cfB0.w, cfB1.x, cfB1.y, cfB1.z, cfB1.w};
        float fbC[8] = {cfC0.x, cfC0.y, cfC0.z, cfC0.w, cfC1.x, cfC1.y, cfC1.z, cfC1.w};
        float fbD[8] = {cfD0.x, cfD0.y, cfD0.z, cfD0.w, cfD1.x, cfD1.y, cfD1.z, cfD1.w};
        float mA0[4] = {0.f,0.f,0.f,0.f};
        float mA1[4] = {0.f,0.f,0.f,0.f};
        float mB0[4] = {0.f,0.f,0.f,0.f};
        float mB1[4] = {0.f,0.f,0.f,0.f};
        float mC0[4] = {0.f,0.f,0.f,0.f};
        float mC1[4] = {0.f,0.f,0.f,0.f};
        float mD0[4] = {0.f,0.f,0.f,0.f};
        float mD1[4] = {0.f,0.f,0.f,0.f};

        #pragma unroll
        for (int s = 0; s < 8; s++) {
            floatx4 aA0 = (floatx4){0.f,0.f,0.f,0.f};
            floatx4 aA1 = (floatx4){0.f,0.f,0.f,0.f};
            floatx4 aB0 = (floatx4){0.f,0.f,0.f,0.f};
            floatx4 aB1 = (floatx4){0.f,0.f,0.f,0.f};
            floatx4 aC0 = (floatx4){0.f,0.f,0.f,0.f};
            floatx4 aC1 = (floatx4){0.f,0.f,0.f,0.f};
            floatx4 aD0 = (floatx4){0.f,0.f,0.f,0.f};
            floatx4 aD1 = (floatx4){0.f,0.f,0.f,0.f};
            short8 aw;
            aw = *(const short8*)&wf[((s*2 + 0)*2 + 0)*512 + l*8];   // ks0, mt0
            aA0 = __builtin_amdgcn_mfma_f32_16x16x32_bf16(aw, cA0, aA0, 0, 0, 0);
            aB0 = __builtin_amdgcn_mfma_f32_16x16x32_bf16(aw, cB0, aB0, 0, 0, 0);
            aC0 = __builtin_amdgcn_mfma_f32_16x16x32_bf16(aw, cC0, aC0, 0, 0, 0);
            aD0 = __builtin_amdgcn_mfma_f32_16x16x32_bf16(aw, cD0, aD0, 0, 0, 0);
            aw = *(const short8*)&wf[((s*2 + 0)*2 + 1)*512 + l*8];   // ks0, mt1
            aA1 = __builtin_amdgcn_mfma_f32_16x16x32_bf16(aw, cA0, aA1, 0, 0, 0);
            aB1 = __builtin_amdgcn_mfma_f32_16x16x32_bf16(aw, cB0, aB1, 0, 0, 0);
            aC1 = __builtin_amdgcn_mfma_f32_16x16x32_bf16(aw, cC0, aC1, 0, 0, 0);
            aD1 = __builtin_amdgcn_mfma_f32_16x16x32_bf16(aw, cD0, aD1, 0, 0, 0);
            aw = *(const short8*)&wf[((s*2 + 1)*2 + 0)*512 + l*8];   // ks1, mt0
            aA0 = __builtin_amdgcn_mfma_f32_16x16x32_bf16(aw, cA1, aA0, 0, 0, 0);
            aB0 = __builtin_amdgcn_mfma_f32_16x16x32_bf16(aw, cB1, aB0, 0, 0, 0);
            aC0 = __builtin_amdgcn_mfma_f32_16x16x32_bf16(aw, cC1, aC0, 0, 0, 0);
            aD0 = __builtin_amdgcn_mfma_f32_16x16x32_bf16(aw, cD1, aD0, 0, 0, 0);
            aw = *(const short8*)&wf[((s*2 + 1)*2 + 1)*512 + l*8];   // ks1, mt1
            aA1 = __builtin_amdgcn_mfma_f32_16x16x32_bf16(aw, cA1, aA1, 0, 0, 0);
            aB1 = __builtin_amdgcn_mfma_f32_16x16x32_bf16(aw, cB1, aB1, 0, 0, 0);
            aC1 = __builtin_amdgcn_mfma_f32_16x16x32_bf16(aw, cC1, aC1, 0, 0, 0);
            aD1 = __builtin_amdgcn_mfma_f32_16x16x32_bf16(aw, cD1, aD1, 0, 0, 0);
            #pragma unroll
            for (int r = 0; r < 4; r++) {
                mA0[r] += fbA[s] * aA0[r];
                mA1[r] += fbA[s] * aA1[r];
                mB0[r] += fbB[s] * aB0[r];
                mB1[r] += fbB[s] * aB1[r];
                mC0[r] += fbC[s] * aC0[r];
                mC1[r] += fbC[s] * aC1[r];
                mD0[r] += fbD[s] * aD0[r];
                mD1[r] += fbD[s] * aD1[r];
            }
        }

        if (p + lo < cnt) {
            ushort4 pk;
            pk.x = f2bf_rn(mA0[0]); pk.y = f2bf_rn(mA0[1]);
            pk.z = f2bf_rn(mA0[2]); pk.w = f2bf_rn(mA0[3]);
            *(ushort4*)(msg + (size_t)cdA*64 + h*32 + 4*g) = pk;
            pk.x = f2bf_rn(mA1[0]); pk.y = f2bf_rn(mA1[1]);
            pk.z = f2bf_rn(mA1[2]); pk.w = f2bf_rn(mA1[3]);
            *(ushort4*)(msg + (size_t)cdA*64 + h*32 + 16 + 4*g) = pk;
        }
        if (p + 16 + lo < cnt) {
            ushort4 pk;
            pk.x = f2bf_rn(mB0[0]); pk.y = f2bf_rn(mB0[1]);
            pk.z = f2bf_rn(mB0[2]); pk.w = f2bf_rn(mB0[3]);
            *(ushort4*)(msg + (size_t)cdB*64 + h*32 + 4*g) = pk;
            pk.x = f2bf_rn(mB1[0]); pk.y = f2bf_rn(mB1[1]);
            pk.z = f2bf_rn(mB1[2]); pk.w = f2bf_rn(mB1[3]);
            *(ushort4*)(msg + (size_t)cdB*64 + h*32 + 16 + 4*g) = pk;
        }
        if (p + 32 + lo < cnt) {
            ushort4 pk;
            pk.x = f2bf_rn(mC0[0]); pk.y = f2bf_rn(mC0[1]);
            pk.z = f2bf_rn(mC0[2]); pk.w = f2bf_rn(mC0[3]);
            *(ushort4*)(msg + (size_t)cdC*64 + h*32 + 4*g) = pk;
            pk.x = f2bf_rn(mC1[0]); pk.y = f2bf_rn(mC1[1]);
            pk.z = f2bf_rn(mC1[2]); pk.w = f2bf_rn(mC1[3]);
            *(ushort4*)(msg + (size_t)cdC*64 + h*32 + 16 + 4*g) = pk;
        }
        if (p + 48 + lo < cnt) {
            ushort4 pk;
            pk.x = f2bf_rn(mD0[0]); pk.y = f2bf_rn(mD0[1]);
            pk.z = f2bf_rn(mD0[2]); pk.w = f2bf_rn(mD0[3]);
            *(ushort4*)(msg + (size_t)cdD*64 + h*32 + 4*g) = pk;
            pk.x = f2bf_rn(mD1[0]); pk.y = f2bf_rn(mD1[1]);
            pk.z = f2bf_rn(mD1[2]); pk.w = f2bf_rn(mD1[3]);
            *(ushort4*)(msg + (size_t)cdD*64 + h*32 + 16 + 4*g) = pk;
        }
    }
#undef LOADT
}

// ---------------- K3: out += rowmean(msg) + bias (fixed-stride rows) ----------------
__global__ void k_final2(const float* __restrict__ bias, const unsigned short* __restrict__ msg,
                         const int* __restrict__ degi, float* __restrict__ out) {
    int n = blockIdx.x * 4 + (threadIdx.x >> 6);
    int o = threadIdx.x & 63;
    int deg = min(degi[n], CAPR);
    const unsigned short* mp = msg + (size_t)n*CAPR*64 + o;
    float v = 0.f;
    for (int j = 0; j < deg; j++) v += bf2f(mp[j*64]);
    v *= 1.0f / (float)max(deg, 1);
    out[n*64 + o] = out[n*64 + o] + v + bias[o];
}

extern "C" void kernel_launch(void* const* d_in, const int* in_sizes, int n_in,
                              void* d_out, int out_size, void* d_ws, size_t ws_size,
                              hipStream_t stream) {
    const float* x      = (const float*)d_in[0];
    const int*   ei     = (const int*)d_in[1];
    const float* pseudo = (const float*)d_in[2];
    const float* weight = (const float*)d_in[3];
    const float* root   = (const float*)d_in[4];
    const float* bias   = (const float*)d_in[5];
    float* out = (float*)d_out;
    char* ws = (char*)d_ws;

    unsigned short* msg    = (unsigned short*)(ws + 0);         // 81,920,000
    float*          basisg = (float*)(ws + 81920000);           // (262144+64)*32 = 8,390,656
    unsigned int*   rowrp  = (unsigned int*)(ws + 90310656);    // 1,048,832
    int*            coli   = (int*)(ws + 91359488);             // 1,048,832
    int*            degi   = (int*)(ws + 92408320);             //    80,000
    int*            curp   = (int*)(ws + 92488320);             //     8,192
    unsigned short* wfg    = (unsigned short*)(ws + 92496512);  // 4,194,304
    unsigned short* xbf    = (unsigned short*)(ws + 96690816);  // 2,560,000 -> 99,250,816 total (ws = 256 MB)

    k_pre   <<<625, 256, 0, stream>>>(x, xbf, degi, curp);
    k_prep  <<<313 + 128 + 313, 256, 0, stream>>>(x, ei, pseudo, curp, degi,
                                                  weight, root, basisg, rowrp, coli, wfg, out);
    k_main  <<<64*2*CPB, 256, 0, stream>>>(wfg, curp, xbf, basisg, rowrp, coli, msg);
    k_final2<<<NN/4, 256, 0, stream>>>(bias, msg, degi, out);
}